// Round 6
// baseline (4745.761 us; speedup 1.0000x reference)
//
#include <hip/hip_runtime.h>
#include <cstdint>
#include <cstddef>

#define B_SZ   4
#define N_PTS  16384
#define M_CENT 2048
#define NSAMP  32
#define C_IN   64
#define H1_DIM 64
#define H2_DIM 128
#define FPS_T  1024
#define NPAIR  (N_PTS / 2)        // 8192 point-pairs
#define PPAIR  (NPAIR / FPS_T)    // 8 pairs per thread
#define H0_STR 68                 // 67 channels padded to 68 for 16B-aligned float4

typedef float v2f __attribute__((ext_vector_type(2)));

// ---------------------------------------------------------------------------
// K1: Farthest-point sampling. One block per batch, xy pairs in 128 KB LDS
// (forces 1 block/CU -> 4 waves/EU -> 128-VGPR budget; r5 proved spill-free),
// z + running dists in registers.
// r5 post-mortem: 68% VALU-busy on active CUs at ~48 inst/pair => the v2f
// math was SCALARIZED and the u64 reduction cost ~100 inst. r6:
//  (a) distance core in inline-asm v_pk_add_f32/v_pk_mul_f32 (VOP3P), with
//      subtract done as add of pre-negated centroid (bit-identical IEEE);
//      element order (sx+sy)+sz == numpy sum order; contract(off) elsewhere.
//  (b) reduction: f32-max butterfly + ballot; single-candidate fast path
//      (index via one shuffle), exact u64 butterfly fallback on true float
//      ties -> numpy first-occurrence argmax semantics preserved exactly.
// ---------------------------------------------------------------------------
__global__ __launch_bounds__(FPS_T) void fps_kernel(const float* __restrict__ xyz,
                                                    float* __restrict__ out_xyz) {
#pragma clang fp contract(off)
  const int b    = blockIdx.x;
  const int t    = threadIdx.x;
  const int lane = t & 63;
  const int wave = t >> 6;           // 16 waves
  const float* bx = xyz + (size_t)b * N_PTS * 3;
  float* ox = out_xyz + (size_t)b * M_CENT * 3;

  __shared__ v2f sX[NPAIR];          // 64 KB: (x_{2p}, x_{2p+1})
  __shared__ v2f sY[NPAIR];          // 64 KB: (y_{2p}, y_{2p+1})
  __shared__ unsigned long long s_key[2][16];

  v2f pzz[PPAIR];                    // (z_{2p}, z_{2p+1}) in registers
  v2f pd[PPAIR];                     // running min-dists, pair-packed

  // stage: 3x float2 loads per pair (8B-aligned: byte offset 24p)
#pragma unroll
  for (int j = 0; j < PPAIR; ++j) {
    const int pp = j * FPS_T + t;
    const float2 a = *reinterpret_cast<const float2*>(bx + 6 * (size_t)pp);      // x0,y0
    const float2 c = *reinterpret_cast<const float2*>(bx + 6 * (size_t)pp + 2);  // z0,x1
    const float2 e = *reinterpret_cast<const float2*>(bx + 6 * (size_t)pp + 4);  // y1,z1
    v2f xv; xv.x = a.x; xv.y = c.y;
    v2f yv; yv.x = a.y; yv.y = e.x;
    v2f zv; zv.x = c.x; zv.y = e.y;
    sX[pp] = xv;
    sY[pp] = yv;
    pzz[j] = zv;
    v2f big; big.x = 1e10f; big.y = 1e10f;
    pd[j] = big;
  }
  // pin z-state so loads can't be re-materialized in-loop
#pragma unroll
  for (int j = 0; j < PPAIR; ++j) asm volatile("" : "+v"(pzz[j]));
  __syncthreads();

  const float* sXf = reinterpret_cast<const float*>(sX);  // x_i at [i]
  const float* sYf = reinterpret_cast<const float*>(sY);  // y_i at [i]

  int cur = 0;  // reference idx0 = 0
  for (int m = 0; m < M_CENT; ++m) {
    const float cx = sXf[cur];          // wave-uniform LDS broadcast
    const float cy = sYf[cur];
    const float cz = bx[cur * 3 + 2];   // L2-hot global
    if (t == 0) { ox[m * 3 + 0] = cx; ox[m * 3 + 1] = cy; ox[m * 3 + 2] = cz; }
    if (m == M_CENT - 1) break;

    // pre-negated centroid: x + (-c) is bit-identical to x - c (IEEE)
    v2f ncx; ncx.x = -cx; ncx.y = -cx;
    v2f ncy; ncy.x = -cy; ncy.y = -cy;
    v2f ncz; ncz.x = -cz; ncz.y = -cz;

    float bv  = -1.0f;  // dists >= 0, so first pair always taken
    int   bjw = 0;      // 2*j + elem of current best (local)
#pragma unroll
    for (int j = 0; j < PPAIR; ++j) {
      const int pp = j * FPS_T + t;
      const v2f xv = sX[pp];            // ds_read_b64, conflict-free (2-way)
      const v2f yv = sY[pp];
      v2f dx, dy, dz, sx, sy, sz, ss, d;
      asm("v_pk_add_f32 %0, %1, %2" : "=v"(dx) : "v"(xv), "v"(ncx));
      asm("v_pk_add_f32 %0, %1, %2" : "=v"(dy) : "v"(yv), "v"(ncy));
      asm("v_pk_add_f32 %0, %1, %2" : "=v"(dz) : "v"(pzz[j]), "v"(ncz));
      asm("v_pk_mul_f32 %0, %1, %1" : "=v"(sx) : "v"(dx));
      asm("v_pk_mul_f32 %0, %1, %1" : "=v"(sy) : "v"(dy));
      asm("v_pk_mul_f32 %0, %1, %1" : "=v"(sz) : "v"(dz));
      asm("v_pk_add_f32 %0, %1, %2" : "=v"(ss) : "v"(sx), "v"(sy));   // x^2+y^2
      asm("v_pk_add_f32 %0, %1, %2" : "=v"(d)  : "v"(ss), "v"(sz));   // +z^2 (numpy order)
      v2f nd;
      nd.x = fminf(pd[j].x, d.x);
      nd.y = fminf(pd[j].y, d.y);
      pd[j] = nd;
      const float pmax = fmaxf(nd.x, nd.y);
      const int   cand = (nd.y > nd.x) ? (2 * j + 1) : (2 * j);  // tie -> elem0 (lower idx)
      const bool better = pmax > bv;    // strict: earlier j wins ties (lower idx)
      bv  = fmaxf(bv, pmax);
      bjw = better ? cand : bjw;
    }
    // global point index of this thread's best
    const int bi = ((bjw >> 1) * FPS_T + t) * 2 + (bjw & 1);

    // ---- wave reduction: f32 max butterfly + single-candidate fast path ----
    const float myv = bv;
    float wv = bv;
#pragma unroll
    for (int off = 32; off >= 1; off >>= 1) wv = fmaxf(wv, __shfl_xor(wv, off));
    const unsigned long long cmask = __ballot(myv == wv);
    int wbi;
    if (__popcll(cmask) == 1) {                      // common: unique winner
      const int winlane = __ffsll((long long)cmask) - 1;
      wbi = __shfl(bi, winlane);
    } else {                                         // exact tie: u64 fallback
      unsigned long long k = ((unsigned long long)__float_as_uint(myv) << 32)
                           | (unsigned int)(N_PTS - bi);
#pragma unroll
      for (int off = 32; off >= 1; off >>= 1) {
        const unsigned long long o = __shfl_xor(k, off);
        k = (k > o) ? k : o;
      }
      wbi = N_PTS - (int)(k & 0xFFFFFFFFULL);
    }

    // ---- cross-wave: exact u64 reduction over 16 per-wave keys ----
    unsigned long long key = ((unsigned long long)__float_as_uint(wv) << 32)
                           | (unsigned int)(N_PTS - wbi);
    const int ph = m & 1;
    if (lane == 0) s_key[ph][wave] = key;
    __syncthreads();
    key = s_key[ph][lane & 15];
#pragma unroll
    for (int off = 8; off >= 1; off >>= 1) {
      const unsigned long long o = __shfl_xor(key, off);
      key = (key > o) ? key : o;
    }
    cur = N_PTS - (int)(key & 0xFFFFFFFFULL);
  }
}

// ---------------------------------------------------------------------------
// K2: Ball query. One wave per centroid: ballot + prefix popcount appends the
// first 32 in-radius indices in index order (== top_k(-order) semantics),
// pads with the first hit. Early exit once 32 found.
// ---------------------------------------------------------------------------
__global__ __launch_bounds__(256) void ballq_kernel(const float* __restrict__ xyz,
                                                    const float* __restrict__ new_xyz,
                                                    int* __restrict__ idx_out) {
#pragma clang fp contract(off)
  const int lane = threadIdx.x & 63;
  const int gid  = blockIdx.x * 4 + (threadIdx.x >> 6);
  if (gid >= B_SZ * M_CENT) return;
  const int b = gid >> 11;  // / M_CENT
  const float* bx = xyz + (size_t)b * N_PTS * 3;
  const float cx = new_xyz[gid * 3 + 0];
  const float cy = new_xyz[gid * 3 + 1];
  const float cz = new_xyz[gid * 3 + 2];
  const float rr = (float)(0.8 * 0.8);  // double 0.64 -> f32 (JAX weak-scalar cast)
  int* out = idx_out + (size_t)gid * NSAMP;

  int count = 0;
  int first = -1;
  for (int base = 0; base < N_PTS; base += 64) {
    const int i = base + lane;
    const float dx = bx[i * 3 + 0] - cx;
    const float dy = bx[i * 3 + 1] - cy;
    const float dz = bx[i * 3 + 2] - cz;
    const float d = (dx * dx + dy * dy) + dz * dz;
    const bool pred = d < rr;
    const unsigned long long mk = __ballot(pred);
    if (pred) {
      const int slot = count + __popcll(mk & ((1ULL << lane) - 1ULL));
      if (slot < NSAMP) out[slot] = i;
    }
    if (first < 0 && mk != 0ULL) first = base + (__ffsll((long long)mk) - 1);
    count += __popcll(mk);
    if (count >= NSAMP) break;
  }
  if (count < NSAMP) {
    for (int k = count + lane; k < NSAMP; k += 64) out[k] = first;  // centroid itself is a hit
  }
}

// ---------------------------------------------------------------------------
// K3: gather + MLP(67->64 relu, 64->128 relu) + max over 32 samples.
// One 128-thread block per centroid. h0/h1 staged in LDS; reads are
// wave-uniform float4 broadcasts; weights coalesced from L1/L2.
// ---------------------------------------------------------------------------
__global__ __launch_bounds__(128) void mlp_kernel(const float* __restrict__ xyz,
                                                  const float* __restrict__ feats,
                                                  const float* __restrict__ new_xyz,
                                                  const int* __restrict__ idx,
                                                  const float* __restrict__ w1,
                                                  const float* __restrict__ b1,
                                                  const float* __restrict__ w2,
                                                  const float* __restrict__ b2,
                                                  float* __restrict__ out_feats) {
  const int gid = blockIdx.x;
  const int t   = threadIdx.x;
  const int b   = gid >> 11;  // / M_CENT

  __shared__ float h0[NSAMP * H0_STR];
  __shared__ float h1[NSAMP * H1_DIM];
  __shared__ int   sidx[NSAMP];

  if (t < NSAMP) sidx[t] = idx[(size_t)gid * NSAMP + t];
  const float cx = new_xyz[gid * 3 + 0];
  const float cy = new_xyz[gid * 3 + 1];
  const float cz = new_xyz[gid * 3 + 2];
  __syncthreads();

  const float* bxyz = xyz + (size_t)b * N_PTS * 3;
  const float* bft  = feats + (size_t)b * N_PTS * C_IN;
  for (int e = t; e < NSAMP * 67; e += 128) {
    const int s = e / 67;
    const int c = e - s * 67;
    const int p = sidx[s];
    float v;
    if (c < 3) {
      const float pc = bxyz[p * 3 + c];
      v = pc - (c == 0 ? cx : (c == 1 ? cy : cz));
    } else {
      v = bft[(size_t)p * C_IN + (c - 3)];
    }
    h0[s * H0_STR + c] = v;
  }
  __syncthreads();

  // layer 1: col = t&63 over H1_DIM, half = t>>6 picks 16 of 32 samples
  {
    const int col  = t & 63;
    const int half = t >> 6;
    float acc[16];
    const float bb = b1[col];
#pragma unroll
    for (int s = 0; s < 16; ++s) acc[s] = bb;
    const float* h0base = h0 + (half * 16) * H0_STR;
    for (int k = 0; k < 64; k += 4) {
      const float w0v = w1[(k + 0) * H1_DIM + col];
      const float w1v = w1[(k + 1) * H1_DIM + col];
      const float w2v = w1[(k + 2) * H1_DIM + col];
      const float w3v = w1[(k + 3) * H1_DIM + col];
#pragma unroll
      for (int s = 0; s < 16; ++s) {
        const float4 h4 = *reinterpret_cast<const float4*>(h0base + s * H0_STR + k);
        acc[s] += h4.x * w0v + h4.y * w1v + h4.z * w2v + h4.w * w3v;
      }
    }
    for (int k = 64; k < 67; ++k) {
      const float wv = w1[k * H1_DIM + col];
#pragma unroll
      for (int s = 0; s < 16; ++s) acc[s] += h0base[s * H0_STR + k] * wv;
    }
#pragma unroll
    for (int s = 0; s < 16; ++s) h1[(half * 16 + s) * H1_DIM + col] = fmaxf(acc[s], 0.0f);
  }
  __syncthreads();

  // layer 2 + max-pool: col = t over H2_DIM
  {
    float acc[32];
    const float bb = b2[t];
#pragma unroll
    for (int s = 0; s < 32; ++s) acc[s] = bb;
    for (int k = 0; k < 64; k += 4) {
      const float w0v = w2[(k + 0) * H2_DIM + t];
      const float w1v = w2[(k + 1) * H2_DIM + t];
      const float w2v = w2[(k + 2) * H2_DIM + t];
      const float w3v = w2[(k + 3) * H2_DIM + t];
#pragma unroll
      for (int s = 0; s < 32; ++s) {
        const float4 h4 = *reinterpret_cast<const float4*>(&h1[s * H1_DIM + k]);
        acc[s] += h4.x * w0v + h4.y * w1v + h4.z * w2v + h4.w * w3v;
      }
    }
    float mx = 0.0f;  // max(relu(v)) == max(0, max(v))
#pragma unroll
    for (int s = 0; s < 32; ++s) mx = fmaxf(mx, acc[s]);
    out_feats[(size_t)gid * H2_DIM + t] = mx;
  }
}

// ---------------------------------------------------------------------------
extern "C" void kernel_launch(void* const* d_in, const int* in_sizes, int n_in,
                              void* d_out, int out_size, void* d_ws, size_t ws_size,
                              hipStream_t stream) {
  const float* xyz   = (const float*)d_in[0];  // (4,16384,3) f32
  const float* feats = (const float*)d_in[1];  // (4,16384,64) f32
  // d_in[2] = bid (unused; output bid is all zeros)
  const float* w1 = (const float*)d_in[3];     // (67,64)
  const float* b1 = (const float*)d_in[4];     // (64,)
  const float* w2 = (const float*)d_in[5];     // (64,128)
  const float* b2 = (const float*)d_in[6];     // (128,)

  float* out       = (float*)d_out;
  float* out_xyz   = out;                                        // (4,2048,3)
  float* out_feats = out + (size_t)B_SZ * M_CENT * 3;            // (4,2048,128)
  float* out_bid   = out_feats + (size_t)B_SZ * M_CENT * H2_DIM; // (4,2048,1) int32 zeros
  int*   idx_ws    = (int*)d_ws;                                 // (4,2048,32) int32, 1 MiB

  hipLaunchKernelGGL(fps_kernel, dim3(B_SZ), dim3(FPS_T), 0, stream, xyz, out_xyz);
  hipLaunchKernelGGL(ballq_kernel, dim3((B_SZ * M_CENT + 3) / 4), dim3(256), 0, stream,
                     xyz, out_xyz, idx_ws);
  hipLaunchKernelGGL(mlp_kernel, dim3(B_SZ * M_CENT), dim3(128), 0, stream,
                     xyz, feats, out_xyz, idx_ws, w1, b1, w2, b2, out_feats);
  hipMemsetAsync(out_bid, 0, (size_t)B_SZ * M_CENT * sizeof(int), stream);
}